// Round 8
// baseline (28002.197 us; speedup 1.0000x reference)
//
#include <hip/hip_runtime.h>
#include <math.h>

// Persistent-kernel LSTM: H=2048, SEQ=4096, fp32 (no fp32 MFMA -> vector ALU).
// v6: 128 WGs x 1024 thr (16 waves), 1 WG/CU (128 CUs active). Wave w of WG g
// owns hidden unit k=g*16+w; each lane holds 4 gate-rows x 32 cols of W_hh
// (128 floats, VGPR/AGPR unified, ~220 regs/wave at 4 waves/SIMD).
//
// Cross-step exchange (tagged data, FULL-line single-transaction publish):
//   hline[2][128][16]: one 64B line per producer WG per slot = the WG's 16
//   h values as fp32 with low mantissa byte = tag (t+1)&0xFF.
//   Producer: waves drop h into LDS pub[16]; barrier; wave0 lanes 0..7 issue
//   eight 8B agent stores in ONE wave instruction = one 64B transaction =
//   one invalidation event per line per step.
//   Consumer thread tid polls ONE 8B load (its units 2*tid, 2*tid+1) with
//   per-word tag validation; poll IS the read. 16K line-requests/round
//   chip-wide (4x less than R7's 65K) and half the lockstep participants --
//   both scale the observed ~3us/step exchange floor.
//   ABA-safe: parity slots + lockstep => stale tags differ by 2 mod 256.
// y_{t-2} drained by WG0/tid0 each step from LDS partials. d_ws: 16 KB.

#define HDIM 2048
#define SEQ 4096
#define NWG 128
#define TPB 1024
#define SLOTW 2048   // unsigned words per slot: 128 lines x 16

__device__ __forceinline__ float sigmoidf_(float x) {
  return 1.0f / (1.0f + expf(-x));
}
__device__ __forceinline__ float tanh_(float x) {
  float e = expf(-2.0f * fabsf(x));
  float r = (1.0f - e) / (1.0f + e);
  return copysignf(r, x);
}

// zero BOTH slots (harness poisons d_ws with 0xAA = tag 170).
// Plain stores OK: end-of-kernel implicit agent release writes L2 back.
__global__ void lstm_init(unsigned* hline) {
  const int i = blockIdx.x * 256 + threadIdx.x;   // 16 blocks x 256 = 4096
  hline[i] = 0u;
}

__global__ __launch_bounds__(TPB, 4) void lstm_persist(
    const float* __restrict__ x, const float* __restrict__ w_ih,
    const float* __restrict__ w_hh, const float* __restrict__ b_ih,
    const float* __restrict__ b_hh, const float* __restrict__ w_out,
    const float* __restrict__ b_out, float* __restrict__ out,
    unsigned* __restrict__ hline)
{
  const int wg   = blockIdx.x;
  const int tid  = threadIdx.x;
  const int wave = tid >> 6;
  const int lane = tid & 63;
  const int k    = wg * 16 + wave;   // this wave's hidden unit

  __shared__ float xs[SEQ];        // 16 KB
  __shared__ float hs[2][HDIM];    // 16 KB, double-buffered
  __shared__ float wys[2][16];     // per-wave y partials, double-buffered
  __shared__ float pub[16];        // gather of this WG's 16 h values

  // ---- one-time: weights into registers ----
  // rows g=0..3 (gates i,f,g,o of unit k): row = k + g*HDIM
  // cols per lane: {256*j + 4*lane + q}, j=0..7, q=0..3  -> 32 float4
  float4 W[32];
  float wx[4], bb[4];
  #pragma unroll
  for (int g = 0; g < 4; ++g) {
    const int row = k + g * HDIM;
    const float* rp = w_hh + (size_t)row * HDIM + lane * 4;
    #pragma unroll
    for (int j = 0; j < 8; ++j)
      W[g * 8 + j] = *(const float4*)(rp + j * 256);
    wx[g] = w_ih[row];
    bb[g] = b_ih[row] + b_hh[row];
  }
  // consumer pair: units 2*tid, 2*tid+1
  const float wo0 = w_out[2 * tid];
  const float wo1 = w_out[2 * tid + 1];
  const float bout = b_out[0];

  for (int i = tid; i < SEQ; i += TPB) xs[i] = x[i];

  float cc = 0.f, hh = 0.f;
  float hv0, hv1;
  __syncthreads();

  for (int t = 0; t < SEQ; ++t) {
    const int par = t & 1;
    const unsigned want = (unsigned)t & 0xFFu;

    // ---- poll own pair: ONE 8B load, both tag bytes == t&0xFF ----
    {
      const unsigned long long* src =
          (const unsigned long long*)(hline + (par ^ 1) * SLOTW) + tid;
      unsigned long long a;
      int guard = 0;
      for (;;) {
        a = __hip_atomic_load(src, __ATOMIC_RELAXED,
                              __HIP_MEMORY_SCOPE_AGENT);
        const int ok = (((unsigned)a & 0xFFu) == want) &
                       (((unsigned)(a >> 32) & 0xFFu) == want);
        if (ok) break;
        __builtin_amdgcn_s_sleep(1);
        if (++guard > (1 << 14)) break;   // protocol-failure escape
      }
      hv0 = __uint_as_float((unsigned)a);
      hv1 = __uint_as_float((unsigned)(a >> 32));
    }

    // ---- stage to LDS (one ds_write_b64) ----
    *(float2*)&hs[par][2 * tid] = make_float2(hv0, hv1);
    __syncthreads();  // B1: hs[par] fully staged; wys[par^1] stable

    // ---- drain y_{t-2} (wys[par^1] written during step t-1) ----
    if (t >= 2 && wg == 0 && tid == 0) {
      float s = bout;
      #pragma unroll
      for (int w = 0; w < 16; ++w) s += wys[par ^ 1][w];
      out[t - 2] = s;
    }

    // ---- z = W_hh @ h (per-lane partials over 32 columns) ----
    float acc[4] = {0.f, 0.f, 0.f, 0.f};
    #pragma unroll
    for (int j = 0; j < 8; ++j) {
      const float4 h4 = *(const float4*)&hs[par][j * 256 + lane * 4];
      #pragma unroll
      for (int g = 0; g < 4; ++g) {
        const float4 w = W[g * 8 + j];
        acc[g] = fmaf(w.x, h4.x, acc[g]);
        acc[g] = fmaf(w.y, h4.y, acc[g]);
        acc[g] = fmaf(w.z, h4.z, acc[g]);
        acc[g] = fmaf(w.w, h4.w, acc[g]);
      }
    }
    // ---- 64-lane butterfly: all lanes end with full row sums ----
    #pragma unroll
    for (int off = 32; off >= 1; off >>= 1) {
      #pragma unroll
      for (int g = 0; g < 4; ++g)
        acc[g] += __shfl_xor(acc[g], off, 64);
    }

    const float xt = xs[t];
    float z[4];
    #pragma unroll
    for (int g = 0; g < 4; ++g) z[g] = fmaf(xt, wx[g], acc[g] + bb[g]);

    // ---- gates (lane-redundant, identical values) ----
    const float gi = sigmoidf_(z[0]), gf = sigmoidf_(z[1]);
    const float gg = tanh_(z[2]), go = sigmoidf_(z[3]);
    cc = gf * cc + gi * gg;
    hh = go * tanh_(cc);

    // ---- off-path: y_{t-1} partial from hv (h_{t-1}) ----
    float sy = fmaf(wo0, hv0, wo1 * hv1);
    #pragma unroll
    for (int off = 32; off >= 1; off >>= 1) sy += __shfl_xor(sy, off, 64);
    if (lane == 0) {
      wys[par][wave] = sy;
      pub[wave] = hh;   // gather for single-transaction publish
    }
    __syncthreads();  // B2: pub[0..16) complete

    // ---- publish: wave0 lanes 0..7, eight 8B stores = ONE 64B transaction ----
    if (wave == 0 && lane < 8) {
      const unsigned tg = (unsigned)(t + 1) & 0xFFu;
      const unsigned ua = (__float_as_uint(pub[2 * lane]) & ~0xFFu) | tg;
      const unsigned ub = (__float_as_uint(pub[2 * lane + 1]) & ~0xFFu) | tg;
      const unsigned long long pay =
          (unsigned long long)ua | ((unsigned long long)ub << 32);
      __hip_atomic_store(
          (unsigned long long*)(hline + par * SLOTW + wg * 16) + lane, pay,
          __ATOMIC_RELAXED, __HIP_MEMORY_SCOPE_AGENT);
    }
  }

  // ---- epilogue ----
  __syncthreads();  // wys[1] (y partials of h_{SEQ-2}) complete
  if (wg == 0 && tid == 0) {
    float s = bout;
    #pragma unroll
    for (int w = 0; w < 16; ++w) s += wys[1][w];
    out[SEQ - 2] = s;
  }

  if (wg == 0) {
    // poll h_{SEQ-1}: slot (SEQ-1)&1 = 1, tag = SEQ&0xFF = 0
    const unsigned want = ((unsigned)SEQ) & 0xFFu;
    const unsigned long long* src =
        (const unsigned long long*)(hline + SLOTW) + tid;
    unsigned long long a = 0;
    int guard = 0;
    for (;;) {
      a = __hip_atomic_load(src, __ATOMIC_RELAXED, __HIP_MEMORY_SCOPE_AGENT);
      const int ok = (((unsigned)a & 0xFFu) == want) &
                     (((unsigned)(a >> 32) & 0xFFu) == want);
      if (ok) break;
      __builtin_amdgcn_s_sleep(1);
      if (++guard > (1 << 14)) break;
    }
    float sy = fmaf(wo0, __uint_as_float((unsigned)a),
                    wo1 * __uint_as_float((unsigned)(a >> 32)));
    #pragma unroll
    for (int off = 32; off >= 1; off >>= 1) sy += __shfl_xor(sy, off, 64);
    if (lane == 0) wys[0][wave] = sy;
    __syncthreads();
    if (tid == 0) {
      float s = bout;
      #pragma unroll
      for (int w = 0; w < 16; ++w) s += wys[0][w];
      out[SEQ - 1] = s;
    }
  }

  // ---- final h, c (exact local fp32 state) ----
  if (lane == 0) {
    out[SEQ + k] = hh;
    out[SEQ + HDIM + k] = cc;
  }
}

extern "C" void kernel_launch(void* const* d_in, const int* in_sizes, int n_in,
                              void* d_out, int out_size, void* d_ws, size_t ws_size,
                              hipStream_t stream) {
  const float* x     = (const float*)d_in[0];
  const float* w_ih  = (const float*)d_in[1];
  const float* w_hh  = (const float*)d_in[2];
  const float* b_ih  = (const float*)d_in[3];
  const float* b_hh  = (const float*)d_in[4];
  const float* w_out = (const float*)d_in[5];
  const float* b_out = (const float*)d_in[6];
  float* out = (float*)d_out;

  // ws layout: [0, 16KB): hline[2][128][16] tagged fp32 (64B line per WG)
  unsigned* hline = (unsigned*)d_ws;

  lstm_init<<<16, 256, 0, stream>>>(hline);
  lstm_persist<<<NWG, TPB, 0, stream>>>(x, w_ih, w_hh, b_ih, b_hh, w_out,
                                        b_out, out, hline);
}